// Round 24
// baseline (846.317 us; speedup 1.0000x reference)
//
#include <hip/hip_runtime.h>
#include <hip/hip_bf16.h>
#include <math.h>

#define B_ 4
#define T_ 2048
#define E_ 512
#define H_ 8
#define D_ 64
#define L_ 4
#define V_ 1024
#define NROWS (B_*T_)   // 8192
#define KBLK 64
#define KVPAD 72        // K/V LDS row stride (bf16): 144B rows, 16B-aligned frags
#define PPAD 72         // Ps row stride (>= KBLK, 16B-aligned)

typedef __hip_bfloat16 bf16;
typedef __attribute__((ext_vector_type(8))) short bf16x8;
typedef __attribute__((ext_vector_type(4))) float f32x4;

__device__ __forceinline__ short f2bf_s(float f) {
    union { bf16 h; short s; } t; t.h = __float2bfloat16(f); return t.s;
}
__device__ __forceinline__ float bf2f_s(short u) {
    union { float f; unsigned int i; } t;
    t.i = ((unsigned int)(unsigned short)u) << 16;
    return t.f;
}

__device__ __forceinline__ void gload_lds16(const bf16* g, bf16* l) {
    __builtin_amdgcn_global_load_lds((const __attribute__((address_space(1))) void*)g,
                                     (__attribute__((address_space(3))) void*)l, 16, 0, 0);
}

__device__ __forceinline__ float gelu_fast(float v) {
    float u = v * (0.7978845608028654f * (1.0f + 0.044715f * v * v));
    float t = 1.0f - 2.0f / (__expf(2.0f * u) + 1.0f);   // tanh(u)
    return 0.5f * v * (1.0f + t);
}

// ---------------- fused fp32 -> bf16 conversion of all weights ----------------
__global__ void f2bf_all(const float* __restrict__ s0, const float* __restrict__ s1,
                         const float* __restrict__ s2, const float* __restrict__ s3,
                         const float* __restrict__ s4, bf16* __restrict__ dst) {
    size_t gi = (size_t)blockIdx.x * 1024 + threadIdx.x * 4;
    const float* src; size_t off;
    if (blockIdx.x < 3072)       { src = s0; off = gi; }
    else if (blockIdx.x < 4096)  { src = s1; off = gi - (size_t)3072 * 1024; }
    else if (blockIdx.x < 8192)  { src = s2; off = gi - (size_t)4096 * 1024; }
    else if (blockIdx.x < 12288) { src = s3; off = gi - (size_t)8192 * 1024; }
    else                         { src = s4; off = gi - (size_t)12288 * 1024; }
    float4 v = *(const float4*)(src + off);
    union { bf16 h[4]; uint2 u; } t;
    t.h[0] = __float2bfloat16(v.x); t.h[1] = __float2bfloat16(v.y);
    t.h[2] = __float2bfloat16(v.z); t.h[3] = __float2bfloat16(v.w);
    *(uint2*)(dst + gi) = t.u;
}

// ---------------- embedding: bf16 x out ----------------
__global__ void embed_kernel(const int* __restrict__ idx, const float* __restrict__ wte,
                             const float* __restrict__ wpe, bf16* __restrict__ x) {
    int i = (blockIdx.x * blockDim.x + threadIdx.x) * 8;
    int row = i >> 9;
    int e = i & (E_ - 1);
    int t = row & (T_ - 1);
    int id = idx[row];
    const float* wa = wte + (size_t)id * E_ + e;
    const float* wp = wpe + (size_t)t * E_ + e;
    float4 a0 = *(const float4*)wa,        a1 = *(const float4*)(wa + 4);
    float4 p0 = *(const float4*)wp,        p1 = *(const float4*)(wp + 4);
    union { bf16 h[8]; uint4 u; } o;
    o.h[0] = __float2bfloat16(a0.x + p0.x); o.h[1] = __float2bfloat16(a0.y + p0.y);
    o.h[2] = __float2bfloat16(a0.z + p0.z); o.h[3] = __float2bfloat16(a0.w + p0.w);
    o.h[4] = __float2bfloat16(a1.x + p1.x); o.h[5] = __float2bfloat16(a1.y + p1.y);
    o.h[6] = __float2bfloat16(a1.z + p1.z); o.h[7] = __float2bfloat16(a1.w + p1.w);
    *(uint4*)(x + i) = o.u;
}

// ---------------- layernorm: bf16 in, bf16 out, one wave per row ----------------
__global__ __launch_bounds__(512) void layernorm_kernel(const bf16* __restrict__ x,
                                 const float* __restrict__ w, const float* __restrict__ b,
                                 bf16* __restrict__ out) {
    int wid = threadIdx.x >> 6, lane = threadIdx.x & 63;
    int row = blockIdx.x * 8 + wid;
    union { uint4 u; short s[8]; } xv;
    xv.u = *(const uint4*)(x + (size_t)row * E_ + lane * 8);
    float a[8];
    #pragma unroll
    for (int k = 0; k < 8; ++k) a[k] = bf2f_s(xv.s[k]);
    float s = 0.0f, q = 0.0f;
    #pragma unroll
    for (int k = 0; k < 8; ++k) { s += a[k]; q += a[k] * a[k]; }
    #pragma unroll
    for (int st = 1; st < 64; st <<= 1) { s += __shfl_xor(s, st); q += __shfl_xor(q, st); }
    float mean = s * (1.0f / E_);
    float var = q * (1.0f / E_) - mean * mean;
    float rstd = rsqrtf(var + 1e-5f);
    float4 w0 = *(const float4*)(w + lane * 8), w1 = *(const float4*)(w + lane * 8 + 4);
    float4 b0 = *(const float4*)(b + lane * 8), b1 = *(const float4*)(b + lane * 8 + 4);
    float wr[8] = {w0.x, w0.y, w0.z, w0.w, w1.x, w1.y, w1.z, w1.w};
    float br[8] = {b0.x, b0.y, b0.z, b0.w, b1.x, b1.y, b1.z, b1.w};
    union { bf16 h[8]; uint4 u; } o;
    #pragma unroll
    for (int k = 0; k < 8; ++k)
        o.h[k] = __float2bfloat16((a[k] - mean) * rstd * wr[k] + br[k]);
    *(uint4*)(out + (size_t)row * E_ + lane * 8) = o.u;
}

// ---------------- bf16 MFMA GEMM (NT), 64x64 tile, BK=64 via dual 32-wide subs ----------
// ACT: 0 none, 1 GELU. OMODE: 0 = fp32 store, 1 = bf16 store, 2 = bf16 residual accumulate.
// QKV=true: q(x0.125)+k -> Cb [row][2E]; v -> Vt [b,h,d,t].
template<int ACT, int OMODE, bool BIAS, bool QKV>
__global__ __launch_bounds__(256) void gemm_mfma64(const bf16* __restrict__ A, const bf16* __restrict__ W,
        const float* __restrict__ bias, float* __restrict__ Cf, bf16* __restrict__ Cb,
        bf16* __restrict__ Vt, int M, int N, int K) {
    __shared__ __align__(16) bf16 As[2][2][64][32];
    __shared__ __align__(16) bf16 Bs[2][2][64][32];
    int tid = threadIdx.x;
    int lane = tid & 63, wid = tid >> 6;
    int wm = (wid >> 1) * 32, wn = (wid & 1) * 32;
    int m0 = blockIdx.y * 64, n0 = blockIdx.x * 64;

    int srow = wid * 16 + (lane >> 2);
    int scol = (lane & 3) * 8;
    const bf16* ga = A + (size_t)(m0 + srow) * K + scol;
    const bf16* gb = W + (size_t)(n0 + srow) * K + scol;
    int fr = lane & 15, fk = (lane >> 4) * 8;

    f32x4 acc[2][2];
    #pragma unroll
    for (int i = 0; i < 2; ++i)
        #pragma unroll
        for (int j = 0; j < 2; ++j) acc[i][j] = (f32x4){0.f, 0.f, 0.f, 0.f};

    gload_lds16(ga,      &As[0][0][wid * 16][0]);
    gload_lds16(ga + 32, &As[0][1][wid * 16][0]);
    gload_lds16(gb,      &Bs[0][0][wid * 16][0]);
    gload_lds16(gb + 32, &Bs[0][1][wid * 16][0]);
    __syncthreads();

    const int nst = K >> 6;                      // K-steps of 64
    for (int t = 0; t < nst; ++t) {
        const int cur = t & 1;
        if (t + 1 < nst) {
            const bf16* ga2 = ga + (t + 1) * 64;
            const bf16* gb2 = gb + (t + 1) * 64;
            gload_lds16(ga2,      &As[cur ^ 1][0][wid * 16][0]);
            gload_lds16(ga2 + 32, &As[cur ^ 1][1][wid * 16][0]);
            gload_lds16(gb2,      &Bs[cur ^ 1][0][wid * 16][0]);
            gload_lds16(gb2 + 32, &Bs[cur ^ 1][1][wid * 16][0]);
        }
        #pragma unroll
        for (int s = 0; s < 2; ++s) {
            bf16x8 af[2], bff[2];
            #pragma unroll
            for (int i = 0; i < 2; ++i) af[i]  = *(const bf16x8*)&As[cur][s][wm + i * 16 + fr][fk];
            #pragma unroll
            for (int j = 0; j < 2; ++j) bff[j] = *(const bf16x8*)&Bs[cur][s][wn + j * 16 + fr][fk];
            #pragma unroll
            for (int i = 0; i < 2; ++i)
                #pragma unroll
                for (int j = 0; j < 2; ++j)
                    acc[i][j] = __builtin_amdgcn_mfma_f32_16x16x32_bf16(af[i], bff[j], acc[i][j], 0, 0, 0);
        }
        __syncthreads();
    }

    int orow = m0 + wm + (lane >> 4) * 4;
    int ocol = n0 + wn + (lane & 15);

    if (QKV && n0 >= 2 * E_) {
        #pragma unroll
        for (int i = 0; i < 2; ++i) {
            int rowb = orow + i * 16;
            int bb = rowb >> 11;
            int t0 = rowb & (T_ - 1);
            #pragma unroll
            for (int j = 0; j < 2; ++j) {
                int col = ocol + j * 16;
                int dg = col - 2 * E_;
                int hh = dg >> 6, dd = dg & 63;
                float bv = BIAS ? bias[col] : 0.0f;
                union { bf16 h[4]; short4 s4; } pk;
                #pragma unroll
                for (int r = 0; r < 4; ++r)
                    pk.h[r] = __float2bfloat16(acc[i][j][r] + bv);
                *(short4*)&Vt[(((size_t)bb * H_ + hh) * D_ + dd) * T_ + t0] = pk.s4;
            }
        }
        return;
    }

    #pragma unroll
    for (int i = 0; i < 2; ++i) {
        #pragma unroll
        for (int j = 0; j < 2; ++j) {
            #pragma unroll
            for (int r = 0; r < 4; ++r) {
                int row = orow + i * 16 + r;
                int col = ocol + j * 16;
                float v = acc[i][j][r];
                if (BIAS) v += bias[col];
                if (ACT == 1) v = gelu_fast(v);
                if (QKV) {
                    if (col < E_) v *= 0.125f;   // fold 1/sqrt(D) into q
                    Cb[(size_t)row * (2 * E_) + col] = __float2bfloat16(v);
                } else {
                    size_t off = (size_t)row * N + col;
                    if (OMODE == 0) Cf[off] = v;
                    else if (OMODE == 1) Cb[off] = __float2bfloat16(v);
                    else Cb[off] = __float2bfloat16(v + __bfloat162float(Cb[off]));
                }
            }
        }
    }
}

// ---------------- attention tile compute (proven round-9/13 body) ----------------
template<bool DOMASK>
__device__ __forceinline__ void attn_tile(
        const short (&Ks)[KBLK][KVPAD], const short (&VsT)[D_][KVPAD],
        short (*Psw)[PPAD], const bf16x8 (&qf)[2],
        float& m_run, float& l_run, f32x4 (&accO)[4],
        int fr, int fg, int k0, int qrow) {
    f32x4 st[4];
    __builtin_amdgcn_s_setprio(1);
    #pragma unroll
    for (int j = 0; j < 4; ++j) {
        f32x4 a = (f32x4){0.f, 0.f, 0.f, 0.f};
        #pragma unroll
        for (int kk = 0; kk < 2; ++kk) {
            bf16x8 kf = *(const bf16x8*)&Ks[j * 16 + fr][kk * 32 + fg * 8];
            a = __builtin_amdgcn_mfma_f32_16x16x32_bf16(kf, qf[kk], a, 0, 0, 0);
        }
        st[j] = a;
    }
    __builtin_amdgcn_s_setprio(0);
    float mx = -INFINITY;
    #pragma unroll
    for (int j = 0; j < 4; ++j)
        #pragma unroll
        for (int r = 0; r < 4; ++r) {
            if (DOMASK && (k0 + j * 16 + fg * 4 + r > qrow)) st[j][r] = -INFINITY;
            mx = fmaxf(mx, st[j][r]);
        }
    mx = fmaxf(mx, __shfl_xor(mx, 16));
    mx = fmaxf(mx, __shfl_xor(mx, 32));
    if (!__all(mx <= m_run + 8.0f)) {          // defer-max
        float mnew = fmaxf(m_run, mx);
        float corr = __expf(m_run - mnew);
        l_run *= corr;
        #pragma unroll
        for (int r = 0; r < 4; ++r) {
            float cr = __shfl(corr, fg * 4 + r);
            #pragma unroll
            for (int n = 0; n < 4; ++n) accO[n][r] *= cr;
        }
        m_run = mnew;
    }
    float rl = 0.0f;
    #pragma unroll
    for (int j = 0; j < 4; ++j) {
        float p0 = __expf(st[j][0] - m_run), p1 = __expf(st[j][1] - m_run);
        float p2 = __expf(st[j][2] - m_run), p3 = __expf(st[j][3] - m_run);
        rl += (p0 + p1) + (p2 + p3);
        short4 pk;
        pk.x = f2bf_s(p0); pk.y = f2bf_s(p1); pk.z = f2bf_s(p2); pk.w = f2bf_s(p3);
        *(short4*)&Psw[fr][j * 16 + fg * 4] = pk;
    }
    rl += __shfl_xor(rl, 16);
    rl += __shfl_xor(rl, 32);
    l_run += rl;
    __builtin_amdgcn_s_setprio(1);
    bf16x8 pa[2];
    #pragma unroll
    for (int kk = 0; kk < 2; ++kk)
        pa[kk] = *(const bf16x8*)&Psw[fr][kk * 32 + fg * 8];
    #pragma unroll
    for (int n = 0; n < 4; ++n)
        #pragma unroll
        for (int kk = 0; kk < 2; ++kk) {
            bf16x8 vb = *(const bf16x8*)&VsT[n * 16 + fr][kk * 32 + fg * 8];
            accO[n] = __builtin_amdgcn_mfma_f32_16x16x32_bf16(pa[kk], vb, accO[n], 0, 0, 0);
        }
    __builtin_amdgcn_s_setprio(0);
}

// ---------------- MFMA flash attention: round-13 structure (27.6 KB LDS, 2 barriers) ----
__global__ __launch_bounds__(256, 4) void attn_mfma(const bf16* __restrict__ qk,
                                                    const bf16* __restrict__ vt,
                                                    bf16* __restrict__ y) {
    __shared__ __align__(16) short Ks[KBLK][KVPAD];
    __shared__ __align__(16) short VsT[D_][KVPAD];
    __shared__ __align__(16) short Ps[4][16][PPAD];
    const int qi = (gridDim.x - 1) - blockIdx.x;        // heaviest first
    const int h = blockIdx.y, b = blockIdx.z;
    const int q0 = qi * 64;
    const int tid = threadIdx.x;
    const int lane = tid & 63, wid = tid >> 6;
    const int fr = lane & 15, fg = lane >> 4;
    const int qmin = q0 + wid * 16;
    const int qrow = qmin + fr;

    const int sr0 = tid >> 3;
    const int sc = (tid & 7) * 8;
    const bf16* kst = qk + (size_t)(b * T_ + sr0) * (2 * E_) + E_ + h * D_ + sc;
    const bf16* vst = vt + ((size_t)(b * H_ + h) * D_ + sr0) * T_ + sc;

    const bf16* qbase = qk + (size_t)(b * T_ + qrow) * (2 * E_) + h * D_;
    bf16x8 qf[2];
    #pragma unroll
    for (int kk = 0; kk < 2; ++kk)
        qf[kk] = *(const bf16x8*)(qbase + kk * 32 + fg * 8);

    float m_run = -INFINITY, l_run = 0.0f;
    f32x4 accO[4];
    #pragma unroll
    for (int n = 0; n < 4; ++n) accO[n] = (f32x4){0.f, 0.f, 0.f, 0.f};

    const int ntiles = qi + 1;

    // prologue: stage tile 0
    {
        uint4 k0r = *(const uint4*)kst;
        uint4 k1r = *(const uint4*)(kst + 32 * (2 * E_));
        uint4 v0r = *(const uint4*)vst;
        uint4 v1r = *(const uint4*)(vst + 32 * T_);
        *(uint4*)&Ks[sr0][sc] = k0r;  *(uint4*)&Ks[sr0 + 32][sc] = k1r;
        *(uint4*)&VsT[sr0][sc] = v0r; *(uint4*)&VsT[sr0 + 32][sc] = v1r;
    }
    __syncthreads();

    for (int kt = 0; kt < ntiles; ++kt) {
        const bool have_next = (kt + 1 < ntiles);
        uint4 nk0, nk1, nv0, nv1;
        if (have_next) {                        // T14: issue loads early, write late
            const bf16* kn = kst + (size_t)(kt + 1) * KBLK * (2 * E_);
            const bf16* vn = vst + (kt + 1) * KBLK;
            nk0 = *(const uint4*)kn; nk1 = *(const uint4*)(kn + 32 * (2 * E_));
            nv0 = *(const uint4*)vn; nv1 = *(const uint4*)(vn + 32 * T_);
        }

        if (kt + 1 == ntiles)
            attn_tile<true >(Ks, VsT, Ps[wid], qf, m_run, l_run, accO, fr, fg, kt * KBLK, qrow);
        else
            attn_tile<false>(Ks, VsT, Ps[wid], qf, m_run, l_run, accO, fr, fg, kt * KBLK, qrow);

        __syncthreads();                        // all waves done reading K/V
        if (have_next) {
            *(uint4*)&Ks[sr0][sc] = nk0;  *(uint4*)&Ks[sr0 + 32][sc] = nk1;
            *(uint4*)&VsT[sr0][sc] = nv0; *(uint4*)&VsT[sr0 + 32][sc] = nv1;
            __syncthreads();                    // writes visible
        }
    }

    // epilogue: O / l
    float linv = 1.0f / l_run;
    #pragma unroll
    for (int r = 0; r < 4; ++r) {
        float lr = __shfl(linv, fg * 4 + r);
        int gq = qmin + fg * 4 + r;
        #pragma unroll
        for (int n = 0; n < 4; ++n)
            y[(size_t)(b * T_ + gq) * E_ + h * D_ + n * 16 + fr] =
                __float2bfloat16(accO[n][r] * lr);
    }
}

extern "C" void kernel_launch(void* const* d_in, const int* in_sizes, int n_in,
                              void* d_out, int out_size, void* d_ws, size_t ws_size,
                              hipStream_t stream) {
    const int*   idx    = (const int*)d_in[0];
    const float* wte    = (const float*)d_in[1];
    const float* wpe    = (const float*)d_in[2];
    const float* ln1_w  = (const float*)d_in[3];
    const float* ln1_b  = (const float*)d_in[4];
    const float* attn_w = (const float*)d_in[5];
    const float* attn_b = (const float*)d_in[6];
    const float* proj_w = (const float*)d_in[7];
    const float* proj_b = (const float*)d_in[8];
    const float* ln2_w  = (const float*)d_in[9];
    const float* ln2_b  = (const float*)d_in[10];
    const float* fc_w   = (const float*)d_in[11];
    const float* fc_b   = (const float*)d_in[12];
    const float* fc2_w  = (const float*)d_in[13];
    const float* fc2_b  = (const float*)d_in[14];
    const float* lnf_w  = (const float*)d_in[15];
    const float* lnf_b  = (const float*)d_in[16];
    float* out = (float*)d_out;

    // ws: x bf16 | hbf bf16 | big bf16[NROWS*4E] | weights bf16
    bf16* x    = (bf16*)d_ws;
    bf16* hbf  = x + (size_t)NROWS * E_;
    bf16* big  = hbf + (size_t)NROWS * E_;
    bf16* qkb  = big;
    bf16* vtb  = big + (size_t)NROWS * 2 * E_;
    bf16* wb   = big + (size_t)NROWS * 4 * E_;
    bf16* attn_wb = wb;
    bf16* proj_wb = attn_wb + (size_t)L_ * 3 * E_ * E_;
    bf16* fc_wb   = proj_wb + (size_t)L_ * E_ * E_;
    bf16* fc2_wb  = fc_wb   + (size_t)L_ * 4 * E_ * E_;
    bf16* wte_b   = fc2_wb  + (size_t)L_ * E_ * 4 * E_;

    f2bf_all<<<12800, 256, 0, stream>>>(attn_w, proj_w, fc_w, fc2_w, wte, wb);
    embed_kernel<<<NROWS * E_ / 2048, 256, 0, stream>>>(idx, wte, wpe, x);

    for (int l = 0; l < L_; ++l) {
        layernorm_kernel<<<NROWS / 8, 512, 0, stream>>>(x, ln1_w + l * E_, ln1_b + l * E_, hbf);
        gemm_mfma64<0, 1, true, true><<<dim3(3 * E_ / 64, NROWS / 64), 256, 0, stream>>>(
            hbf, attn_wb + (size_t)l * 3 * E_ * E_, attn_b + l * 3 * E_, nullptr, qkb, vtb,
            NROWS, 3 * E_, E_);
        attn_mfma<<<dim3(T_ / 64, H_, B_), 256, 0, stream>>>(qkb, vtb, hbf);
        gemm_mfma64<0, 2, true, false><<<dim3(E_ / 64, NROWS / 64), 256, 0, stream>>>(
            hbf, proj_wb + (size_t)l * E_ * E_, proj_b + l * E_, nullptr, x, nullptr,
            NROWS, E_, E_);
        layernorm_kernel<<<NROWS / 8, 512, 0, stream>>>(x, ln2_w + l * E_, ln2_b + l * E_, hbf);
        gemm_mfma64<1, 1, true, false><<<dim3(4 * E_ / 64, NROWS / 64), 256, 0, stream>>>(
            hbf, fc_wb + (size_t)l * 4 * E_ * E_, fc_b + l * 4 * E_, nullptr, big, nullptr,
            NROWS, 4 * E_, E_);
        gemm_mfma64<0, 2, true, false><<<dim3(E_ / 64, NROWS / 64), 256, 0, stream>>>(
            big, fc2_wb + (size_t)l * E_ * 4 * E_, fc2_b + l * E_, nullptr, x, nullptr,
            NROWS, E_, 4 * E_);
    }
    layernorm_kernel<<<NROWS / 8, 512, 0, stream>>>(x, lnf_w, lnf_b, hbf);
    gemm_mfma64<0, 0, false, false><<<dim3(V_ / 64, NROWS / 64), 256, 0, stream>>>(
        hbf, wte_b, nullptr, out, nullptr, nullptr, NROWS, V_, E_);
}

// Round 25
// 839.291 us; speedup vs baseline: 1.0084x; 1.0084x over previous
//
#include <hip/hip_runtime.h>
#include <hip/hip_bf16.h>
#include <math.h>

#define B_ 4
#define T_ 2048
#define E_ 512
#define H_ 8
#define D_ 64
#define L_ 4
#define V_ 1024
#define NROWS (B_*T_)   // 8192
#define KBLK 64
#define KVPAD 72        // K/V LDS row stride (bf16): 144B rows, 16B-aligned frags
#define PPAD 72         // Ps row stride (>= KBLK, 16B-aligned)

typedef __hip_bfloat16 bf16;
typedef __attribute__((ext_vector_type(8))) short bf16x8;
typedef __attribute__((ext_vector_type(4))) float f32x4;

__device__ __forceinline__ short f2bf_s(float f) {
    union { bf16 h; short s; } t; t.h = __float2bfloat16(f); return t.s;
}
__device__ __forceinline__ float bf2f_s(short u) {
    union { float f; unsigned int i; } t;
    t.i = ((unsigned int)(unsigned short)u) << 16;
    return t.f;
}

__device__ __forceinline__ void gload_lds16(const bf16* g, bf16* l) {
    __builtin_amdgcn_global_load_lds((const __attribute__((address_space(1))) void*)g,
                                     (__attribute__((address_space(3))) void*)l, 16, 0, 0);
}

__device__ __forceinline__ float gelu_fast(float v) {
    float u = v * (0.7978845608028654f * (1.0f + 0.044715f * v * v));
    float t = 1.0f - 2.0f / (__expf(2.0f * u) + 1.0f);   // tanh(u)
    return 0.5f * v * (1.0f + t);
}

// ---------------- fused fp32 -> bf16 conversion of all weights ----------------
__global__ void f2bf_all(const float* __restrict__ s0, const float* __restrict__ s1,
                         const float* __restrict__ s2, const float* __restrict__ s3,
                         const float* __restrict__ s4, bf16* __restrict__ dst) {
    size_t gi = (size_t)blockIdx.x * 1024 + threadIdx.x * 4;
    const float* src; size_t off;
    if (blockIdx.x < 3072)       { src = s0; off = gi; }
    else if (blockIdx.x < 4096)  { src = s1; off = gi - (size_t)3072 * 1024; }
    else if (blockIdx.x < 8192)  { src = s2; off = gi - (size_t)4096 * 1024; }
    else if (blockIdx.x < 12288) { src = s3; off = gi - (size_t)8192 * 1024; }
    else                         { src = s4; off = gi - (size_t)12288 * 1024; }
    float4 v = *(const float4*)(src + off);
    union { bf16 h[4]; uint2 u; } t;
    t.h[0] = __float2bfloat16(v.x); t.h[1] = __float2bfloat16(v.y);
    t.h[2] = __float2bfloat16(v.z); t.h[3] = __float2bfloat16(v.w);
    *(uint2*)(dst + gi) = t.u;
}

// ---------------- embedding: bf16 x out ----------------
__global__ void embed_kernel(const int* __restrict__ idx, const float* __restrict__ wte,
                             const float* __restrict__ wpe, bf16* __restrict__ x) {
    int i = (blockIdx.x * blockDim.x + threadIdx.x) * 8;
    int row = i >> 9;
    int e = i & (E_ - 1);
    int t = row & (T_ - 1);
    int id = idx[row];
    const float* wa = wte + (size_t)id * E_ + e;
    const float* wp = wpe + (size_t)t * E_ + e;
    float4 a0 = *(const float4*)wa,        a1 = *(const float4*)(wa + 4);
    float4 p0 = *(const float4*)wp,        p1 = *(const float4*)(wp + 4);
    union { bf16 h[8]; uint4 u; } o;
    o.h[0] = __float2bfloat16(a0.x + p0.x); o.h[1] = __float2bfloat16(a0.y + p0.y);
    o.h[2] = __float2bfloat16(a0.z + p0.z); o.h[3] = __float2bfloat16(a0.w + p0.w);
    o.h[4] = __float2bfloat16(a1.x + p1.x); o.h[5] = __float2bfloat16(a1.y + p1.y);
    o.h[6] = __float2bfloat16(a1.z + p1.z); o.h[7] = __float2bfloat16(a1.w + p1.w);
    *(uint4*)(x + i) = o.u;
}

// ---------------- layernorm: bf16 in, bf16 out, one wave per row ----------------
__global__ __launch_bounds__(512) void layernorm_kernel(const bf16* __restrict__ x,
                                 const float* __restrict__ w, const float* __restrict__ b,
                                 bf16* __restrict__ out) {
    int wid = threadIdx.x >> 6, lane = threadIdx.x & 63;
    int row = blockIdx.x * 8 + wid;
    union { uint4 u; short s[8]; } xv;
    xv.u = *(const uint4*)(x + (size_t)row * E_ + lane * 8);
    float a[8];
    #pragma unroll
    for (int k = 0; k < 8; ++k) a[k] = bf2f_s(xv.s[k]);
    float s = 0.0f, q = 0.0f;
    #pragma unroll
    for (int k = 0; k < 8; ++k) { s += a[k]; q += a[k] * a[k]; }
    #pragma unroll
    for (int st = 1; st < 64; st <<= 1) { s += __shfl_xor(s, st); q += __shfl_xor(q, st); }
    float mean = s * (1.0f / E_);
    float var = q * (1.0f / E_) - mean * mean;
    float rstd = rsqrtf(var + 1e-5f);
    float4 w0 = *(const float4*)(w + lane * 8), w1 = *(const float4*)(w + lane * 8 + 4);
    float4 b0 = *(const float4*)(b + lane * 8), b1 = *(const float4*)(b + lane * 8 + 4);
    float wr[8] = {w0.x, w0.y, w0.z, w0.w, w1.x, w1.y, w1.z, w1.w};
    float br[8] = {b0.x, b0.y, b0.z, b0.w, b1.x, b1.y, b1.z, b1.w};
    union { bf16 h[8]; uint4 u; } o;
    #pragma unroll
    for (int k = 0; k < 8; ++k)
        o.h[k] = __float2bfloat16((a[k] - mean) * rstd * wr[k] + br[k]);
    *(uint4*)(out + (size_t)row * E_ + lane * 8) = o.u;
}

// ---------------- bf16 MFMA GEMM (NT), 128x128 tile, BK=32 dbuf pipeline ----------------
// OMODE: 0 = fp32 store, 1 = bf16 store, 2 = bf16 residual accumulate (fp32 math)
template<int ACT, int OMODE, bool BIAS>
__global__ __launch_bounds__(256) void gemm_mfma(const bf16* __restrict__ A, const bf16* __restrict__ W,
        const float* __restrict__ bias, float* __restrict__ Cf, bf16* __restrict__ Cb,
        int M, int N, int K) {
    __shared__ __align__(16) bf16 As[2][128][32];
    __shared__ __align__(16) bf16 Bs[2][128][32];
    int tid = threadIdx.x;
    int lane = tid & 63, wid = tid >> 6;
    int wm = (wid >> 1) * 64, wn = (wid & 1) * 64;
    int m0 = blockIdx.y * 128, n0 = blockIdx.x * 128;

    int srow = wid * 32 + (lane >> 2);
    int scol = (lane & 3) * 8;
    const bf16* ga = A + (size_t)(m0 + srow) * K + scol;
    const bf16* gb = W + (size_t)(n0 + srow) * K + scol;
    int fr = lane & 15, fk = (lane >> 4) * 8;

    f32x4 acc[4][4];
    #pragma unroll
    for (int i = 0; i < 4; ++i)
        #pragma unroll
        for (int j = 0; j < 4; ++j) acc[i][j] = (f32x4){0.f, 0.f, 0.f, 0.f};

    gload_lds16(ga,          &As[0][wid * 32][0]);
    gload_lds16(ga + 16 * K, &As[0][wid * 32 + 16][0]);
    gload_lds16(gb,          &Bs[0][wid * 32][0]);
    gload_lds16(gb + 16 * K, &Bs[0][wid * 32 + 16][0]);
    __syncthreads();

    const int nst = K >> 5;
    for (int t = 0; t < nst; ++t) {
        const int cur = t & 1;
        if (t + 1 < nst) {
            const bf16* ga2 = ga + (t + 1) * 32;
            const bf16* gb2 = gb + (t + 1) * 32;
            gload_lds16(ga2,          &As[cur ^ 1][wid * 32][0]);
            gload_lds16(ga2 + 16 * K, &As[cur ^ 1][wid * 32 + 16][0]);
            gload_lds16(gb2,          &Bs[cur ^ 1][wid * 32][0]);
            gload_lds16(gb2 + 16 * K, &Bs[cur ^ 1][wid * 32 + 16][0]);
        }
        bf16x8 af[4], bff[4];
        #pragma unroll
        for (int i = 0; i < 4; ++i) af[i]  = *(const bf16x8*)&As[cur][wm + i * 16 + fr][fk];
        #pragma unroll
        for (int j = 0; j < 4; ++j) bff[j] = *(const bf16x8*)&Bs[cur][wn + j * 16 + fr][fk];
        #pragma unroll
        for (int i = 0; i < 4; ++i)
            #pragma unroll
            for (int j = 0; j < 4; ++j)
                acc[i][j] = __builtin_amdgcn_mfma_f32_16x16x32_bf16(af[i], bff[j], acc[i][j], 0, 0, 0);
        __syncthreads();
    }

    int orow = m0 + wm + (lane >> 4) * 4;
    int ocol = n0 + wn + (lane & 15);
    #pragma unroll
    for (int i = 0; i < 4; ++i) {
        #pragma unroll
        for (int j = 0; j < 4; ++j) {
            #pragma unroll
            for (int r = 0; r < 4; ++r) {
                int row = orow + i * 16 + r;
                int col = ocol + j * 16;
                float v = acc[i][j][r];
                if (BIAS) v += bias[col];
                if (ACT == 1) v = gelu_fast(v);
                size_t off = (size_t)row * N + col;
                if (OMODE == 0) Cf[off] = v;
                else if (OMODE == 1) Cb[off] = __float2bfloat16(v);
                else Cb[off] = __float2bfloat16(v + __bfloat162float(Cb[off]));
            }
        }
    }
}

// ---------------- bf16 MFMA GEMM (NT), 64x64 tile, BK=64 via dual 32-wide subs ----------
// OMODE: 0 = fp32 store, 1 = bf16 store, 2 = bf16 residual accumulate (fp32 math)
// QKV=true: q(x0.125)+k -> Cb [row][2E]; v -> Vt [b,h,d,t].
template<int OMODE, bool BIAS, bool QKV>
__global__ __launch_bounds__(256) void gemm_mfma64(const bf16* __restrict__ A, const bf16* __restrict__ W,
        const float* __restrict__ bias, float* __restrict__ Cf, bf16* __restrict__ Cb,
        bf16* __restrict__ Vt, int M, int N, int K) {
    __shared__ __align__(16) bf16 As[2][2][64][32];
    __shared__ __align__(16) bf16 Bs[2][2][64][32];
    int tid = threadIdx.x;
    int lane = tid & 63, wid = tid >> 6;
    int wm = (wid >> 1) * 32, wn = (wid & 1) * 32;
    int m0 = blockIdx.y * 64, n0 = blockIdx.x * 64;

    int srow = wid * 16 + (lane >> 2);
    int scol = (lane & 3) * 8;
    const bf16* ga = A + (size_t)(m0 + srow) * K + scol;
    const bf16* gb = W + (size_t)(n0 + srow) * K + scol;
    int fr = lane & 15, fk = (lane >> 4) * 8;

    f32x4 acc[2][2];
    #pragma unroll
    for (int i = 0; i < 2; ++i)
        #pragma unroll
        for (int j = 0; j < 2; ++j) acc[i][j] = (f32x4){0.f, 0.f, 0.f, 0.f};

    gload_lds16(ga,      &As[0][0][wid * 16][0]);
    gload_lds16(ga + 32, &As[0][1][wid * 16][0]);
    gload_lds16(gb,      &Bs[0][0][wid * 16][0]);
    gload_lds16(gb + 32, &Bs[0][1][wid * 16][0]);
    __syncthreads();

    const int nst = K >> 6;                      // K-steps of 64
    for (int t = 0; t < nst; ++t) {
        const int cur = t & 1;
        if (t + 1 < nst) {
            const bf16* ga2 = ga + (t + 1) * 64;
            const bf16* gb2 = gb + (t + 1) * 64;
            gload_lds16(ga2,      &As[cur ^ 1][0][wid * 16][0]);
            gload_lds16(ga2 + 32, &As[cur ^ 1][1][wid * 16][0]);
            gload_lds16(gb2,      &Bs[cur ^ 1][0][wid * 16][0]);
            gload_lds16(gb2 + 32, &Bs[cur ^ 1][1][wid * 16][0]);
        }
        #pragma unroll
        for (int s = 0; s < 2; ++s) {
            bf16x8 af[2], bff[2];
            #pragma unroll
            for (int i = 0; i < 2; ++i) af[i]  = *(const bf16x8*)&As[cur][s][wm + i * 16 + fr][fk];
            #pragma unroll
            for (int j = 0; j < 2; ++j) bff[j] = *(const bf16x8*)&Bs[cur][s][wn + j * 16 + fr][fk];
            #pragma unroll
            for (int i = 0; i < 2; ++i)
                #pragma unroll
                for (int j = 0; j < 2; ++j)
                    acc[i][j] = __builtin_amdgcn_mfma_f32_16x16x32_bf16(af[i], bff[j], acc[i][j], 0, 0, 0);
        }
        __syncthreads();
    }

    int orow = m0 + wm + (lane >> 4) * 4;
    int ocol = n0 + wn + (lane & 15);

    if (QKV && n0 >= 2 * E_) {
        #pragma unroll
        for (int i = 0; i < 2; ++i) {
            int rowb = orow + i * 16;
            int bb = rowb >> 11;
            int t0 = rowb & (T_ - 1);
            #pragma unroll
            for (int j = 0; j < 2; ++j) {
                int col = ocol + j * 16;
                int dg = col - 2 * E_;
                int hh = dg >> 6, dd = dg & 63;
                float bv = BIAS ? bias[col] : 0.0f;
                union { bf16 h[4]; short4 s4; } pk;
                #pragma unroll
                for (int r = 0; r < 4; ++r)
                    pk.h[r] = __float2bfloat16(acc[i][j][r] + bv);
                *(short4*)&Vt[(((size_t)bb * H_ + hh) * D_ + dd) * T_ + t0] = pk.s4;
            }
        }
        return;
    }

    #pragma unroll
    for (int i = 0; i < 2; ++i) {
        #pragma unroll
        for (int j = 0; j < 2; ++j) {
            #pragma unroll
            for (int r = 0; r < 4; ++r) {
                int row = orow + i * 16 + r;
                int col = ocol + j * 16;
                float v = acc[i][j][r];
                if (BIAS) v += bias[col];
                if (QKV) {
                    if (col < E_) v *= 0.125f;   // fold 1/sqrt(D) into q
                    Cb[(size_t)row * (2 * E_) + col] = __float2bfloat16(v);
                } else {
                    size_t off = (size_t)row * N + col;
                    if (OMODE == 0) Cf[off] = v;
                    else if (OMODE == 1) Cb[off] = __float2bfloat16(v);
                    else Cb[off] = __float2bfloat16(v + __bfloat162float(Cb[off]));
                }
            }
        }
    }
}

// ---------------- attention tile compute (proven round-9/13 body) ----------------
template<bool DOMASK>
__device__ __forceinline__ void attn_tile(
        const short (&Ks)[KBLK][KVPAD], const short (&VsT)[D_][KVPAD],
        short (*Psw)[PPAD], const bf16x8 (&qf)[2],
        float& m_run, float& l_run, f32x4 (&accO)[4],
        int fr, int fg, int k0, int qrow) {
    f32x4 st[4];
    __builtin_amdgcn_s_setprio(1);
    #pragma unroll
    for (int j = 0; j < 4; ++j) {
        f32x4 a = (f32x4){0.f, 0.f, 0.f, 0.f};
        #pragma unroll
        for (int kk = 0; kk < 2; ++kk) {
            bf16x8 kf = *(const bf16x8*)&Ks[j * 16 + fr][kk * 32 + fg * 8];
            a = __builtin_amdgcn_mfma_f32_16x16x32_bf16(kf, qf[kk], a, 0, 0, 0);
        }
        st[j] = a;
    }
    __builtin_amdgcn_s_setprio(0);
    float mx = -INFINITY;
    #pragma unroll
    for (int j = 0; j < 4; ++j)
        #pragma unroll
        for (int r = 0; r < 4; ++r) {
            if (DOMASK && (k0 + j * 16 + fg * 4 + r > qrow)) st[j][r] = -INFINITY;
            mx = fmaxf(mx, st[j][r]);
        }
    mx = fmaxf(mx, __shfl_xor(mx, 16));
    mx = fmaxf(mx, __shfl_xor(mx, 32));
    if (!__all(mx <= m_run + 8.0f)) {          // defer-max
        float mnew = fmaxf(m_run, mx);
        float corr = __expf(m_run - mnew);
        l_run *= corr;
        #pragma unroll
        for (int r = 0; r < 4; ++r) {
            float cr = __shfl(corr, fg * 4 + r);
            #pragma unroll
            for (int n = 0; n < 4; ++n) accO[n][r] *= cr;
        }
        m_run = mnew;
    }
    float rl = 0.0f;
    #pragma unroll
    for (int j = 0; j < 4; ++j) {
        float p0 = __expf(st[j][0] - m_run), p1 = __expf(st[j][1] - m_run);
        float p2 = __expf(st[j][2] - m_run), p3 = __expf(st[j][3] - m_run);
        rl += (p0 + p1) + (p2 + p3);
        short4 pk;
        pk.x = f2bf_s(p0); pk.y = f2bf_s(p1); pk.z = f2bf_s(p2); pk.w = f2bf_s(p3);
        *(short4*)&Psw[fr][j * 16 + fg * 4] = pk;
    }
    rl += __shfl_xor(rl, 16);
    rl += __shfl_xor(rl, 32);
    l_run += rl;
    __builtin_amdgcn_s_setprio(1);
    bf16x8 pa[2];
    #pragma unroll
    for (int kk = 0; kk < 2; ++kk)
        pa[kk] = *(const bf16x8*)&Psw[fr][kk * 32 + fg * 8];
    #pragma unroll
    for (int n = 0; n < 4; ++n)
        #pragma unroll
        for (int kk = 0; kk < 2; ++kk) {
            bf16x8 vb = *(const bf16x8*)&VsT[n * 16 + fr][kk * 32 + fg * 8];
            accO[n] = __builtin_amdgcn_mfma_f32_16x16x32_bf16(pa[kk], vb, accO[n], 0, 0, 0);
        }
    __builtin_amdgcn_s_setprio(0);
}

// ---------------- MFMA flash attention: round-13 structure (27.6 KB LDS, 2 barriers) ----
__global__ __launch_bounds__(256, 4) void attn_mfma(const bf16* __restrict__ qk,
                                                    const bf16* __restrict__ vt,
                                                    bf16* __restrict__ y) {
    __shared__ __align__(16) short Ks[KBLK][KVPAD];
    __shared__ __align__(16) short VsT[D_][KVPAD];
    __shared__ __align__(16) short Ps[4][16][PPAD];
    const int qi = (gridDim.x - 1) - blockIdx.x;        // heaviest first
    const int h = blockIdx.y, b = blockIdx.z;
    const int q0 = qi * 64;
    const int tid = threadIdx.x;
    const int lane = tid & 63, wid = tid >> 6;
    const int fr = lane & 15, fg = lane >> 4;
    const int qmin = q0 + wid * 16;
    const int qrow = qmin + fr;

    const int sr0 = tid >> 3;
    const int sc = (tid & 7) * 8;
    const bf16* kst = qk + (size_t)(b * T_ + sr0) * (2 * E_) + E_ + h * D_ + sc;
    const bf16* vst = vt + ((size_t)(b * H_ + h) * D_ + sr0) * T_ + sc;

    const bf16* qbase = qk + (size_t)(b * T_ + qrow) * (2 * E_) + h * D_;
    bf16x8 qf[2];
    #pragma unroll
    for (int kk = 0; kk < 2; ++kk)
        qf[kk] = *(const bf16x8*)(qbase + kk * 32 + fg * 8);

    float m_run = -INFINITY, l_run = 0.0f;
    f32x4 accO[4];
    #pragma unroll
    for (int n = 0; n < 4; ++n) accO[n] = (f32x4){0.f, 0.f, 0.f, 0.f};

    const int ntiles = qi + 1;

    // prologue: stage tile 0
    {
        uint4 k0r = *(const uint4*)kst;
        uint4 k1r = *(const uint4*)(kst + 32 * (2 * E_));
        uint4 v0r = *(const uint4*)vst;
        uint4 v1r = *(const uint4*)(vst + 32 * T_);
        *(uint4*)&Ks[sr0][sc] = k0r;  *(uint4*)&Ks[sr0 + 32][sc] = k1r;
        *(uint4*)&VsT[sr0][sc] = v0r; *(uint4*)&VsT[sr0 + 32][sc] = v1r;
    }
    __syncthreads();

    for (int kt = 0; kt < ntiles; ++kt) {
        const bool have_next = (kt + 1 < ntiles);
        uint4 nk0, nk1, nv0, nv1;
        if (have_next) {                        // T14: issue loads early, write late
            const bf16* kn = kst + (size_t)(kt + 1) * KBLK * (2 * E_);
            const bf16* vn = vst + (kt + 1) * KBLK;
            nk0 = *(const uint4*)kn; nk1 = *(const uint4*)(kn + 32 * (2 * E_));
            nv0 = *(const uint4*)vn; nv1 = *(const uint4*)(vn + 32 * T_);
        }

        if (kt + 1 == ntiles)
            attn_tile<true >(Ks, VsT, Ps[wid], qf, m_run, l_run, accO, fr, fg, kt * KBLK, qrow);
        else
            attn_tile<false>(Ks, VsT, Ps[wid], qf, m_run, l_run, accO, fr, fg, kt * KBLK, qrow);

        __syncthreads();                        // all waves done reading K/V
        if (have_next) {
            *(uint4*)&Ks[sr0][sc] = nk0;  *(uint4*)&Ks[sr0 + 32][sc] = nk1;
            *(uint4*)&VsT[sr0][sc] = nv0; *(uint4*)&VsT[sr0 + 32][sc] = nv1;
            __syncthreads();                    // writes visible
        }
    }

    // epilogue: O / l
    float linv = 1.0f / l_run;
    #pragma unroll
    for (int r = 0; r < 4; ++r) {
        float lr = __shfl(linv, fg * 4 + r);
        int gq = qmin + fg * 4 + r;
        #pragma unroll
        for (int n = 0; n < 4; ++n)
            y[(size_t)(b * T_ + gq) * E_ + h * D_ + n * 16 + fr] =
                __float2bfloat16(accO[n][r] * lr);
    }
}

extern "C" void kernel_launch(void* const* d_in, const int* in_sizes, int n_in,
                              void* d_out, int out_size, void* d_ws, size_t ws_size,
                              hipStream_t stream) {
    const int*   idx    = (const int*)d_in[0];
    const float* wte    = (const float*)d_in[1];
    const float* wpe    = (const float*)d_in[2];
    const float* ln1_w  = (const float*)d_in[3];
    const float* ln1_b  = (const float*)d_in[4];
    const float* attn_w = (const float*)d_in[5];
    const float* attn_b = (const float*)d_in[6];
    const float* proj_w = (const float*)d_in[7];
    const float* proj_b = (const float*)d_in[8];
    const float* ln2_w  = (const float*)d_in[9];
    const float* ln2_b  = (const float*)d_in[10];
    const float* fc_w   = (const float*)d_in[11];
    const float* fc_b   = (const float*)d_in[12];
    const float* fc2_w  = (const float*)d_in[13];
    const float* fc2_b  = (const float*)d_in[14];
    const float* lnf_w  = (const float*)d_in[15];
    const float* lnf_b  = (const float*)d_in[16];
    float* out = (float*)d_out;

    // ws: x bf16 | hbf bf16 | big bf16[NROWS*4E] | weights bf16
    bf16* x    = (bf16*)d_ws;
    bf16* hbf  = x + (size_t)NROWS * E_;
    bf16* big  = hbf + (size_t)NROWS * E_;
    bf16* qkb  = big;
    bf16* vtb  = big + (size_t)NROWS * 2 * E_;
    bf16* wb   = big + (size_t)NROWS * 4 * E_;
    bf16* attn_wb = wb;
    bf16* proj_wb = attn_wb + (size_t)L_ * 3 * E_ * E_;
    bf16* fc_wb   = proj_wb + (size_t)L_ * E_ * E_;
    bf16* fc2_wb  = fc_wb   + (size_t)L_ * 4 * E_ * E_;
    bf16* wte_b   = fc2_wb  + (size_t)L_ * E_ * 4 * E_;

    f2bf_all<<<12800, 256, 0, stream>>>(attn_w, proj_w, fc_w, fc2_w, wte, wb);
    embed_kernel<<<NROWS * E_ / 2048, 256, 0, stream>>>(idx, wte, wpe, x);

    for (int l = 0; l < L_; ++l) {
        layernorm_kernel<<<NROWS / 8, 512, 0, stream>>>(x, ln1_w + l * E_, ln1_b + l * E_, hbf);
        gemm_mfma64<1, true, true><<<dim3(3 * E_ / 64, NROWS / 64), 256, 0, stream>>>(
            hbf, attn_wb + (size_t)l * 3 * E_ * E_, attn_b + l * 3 * E_, nullptr, qkb, vtb,
            NROWS, 3 * E_, E_);
        attn_mfma<<<dim3(T_ / 64, H_, B_), 256, 0, stream>>>(qkb, vtb, hbf);
        gemm_mfma64<2, true, false><<<dim3(E_ / 64, NROWS / 64), 256, 0, stream>>>(
            hbf, proj_wb + (size_t)l * E_ * E_, proj_b + l * E_, nullptr, x, nullptr,
            NROWS, E_, E_);
        layernorm_kernel<<<NROWS / 8, 512, 0, stream>>>(x, ln2_w + l * E_, ln2_b + l * E_, hbf);
        gemm_mfma<1, 1, true><<<dim3(4 * E_ / 128, NROWS / 128), 256, 0, stream>>>(
            hbf, fc_wb + (size_t)l * 4 * E_ * E_, fc_b + l * 4 * E_, nullptr, big,
            NROWS, 4 * E_, E_);
        gemm_mfma64<2, true, false><<<dim3(E_ / 64, NROWS / 64), 256, 0, stream>>>(
            big, fc2_wb + (size_t)l * E_ * 4 * E_, fc2_b + l * E_, nullptr, x, nullptr,
            NROWS, E_, 4 * E_);
    }
    layernorm_kernel<<<NROWS / 8, 512, 0, stream>>>(x, lnf_w, lnf_b, hbf);
    gemm_mfma64<0, false, false><<<dim3(V_ / 64, NROWS / 64), 256, 0, stream>>>(
        hbf, wte_b, nullptr, out, nullptr, nullptr, NROWS, V_, E_);
}